// Round 9
// baseline (401.280 us; speedup 1.0000x reference)
//
#include <hip/hip_runtime.h>

#define NN 50000
#define EE 800000
#define NEG 0.2f
#define NBLK_SCAN 196   // ceil(NN/256)
#define NBG 391         // gemm grid: 1564 waves x 2 mtiles >= 3125
#define NBE 196         // expert grid: 784 waves x 4 mtiles >= 3125
#define NBKT 98         // dst buckets of 512
#define EPB 2048        // edges per binA block
#define NSEG 391        // ceil(EE/EPB)

typedef __attribute__((ext_vector_type(8))) short s8;
typedef __attribute__((ext_vector_type(4))) float f4;

__device__ __forceinline__ float leaky(float x) { return x > 0.f ? x : NEG * x; }
__device__ __forceinline__ unsigned bf16r(float x) {
    unsigned u = __float_as_uint(x);
    return (u + 0x7fffu + ((u >> 16) & 1u)) >> 16;
}
__device__ __forceinline__ float lo16(unsigned p) { return __uint_as_float(p << 16); }
__device__ __forceinline__ float hi16(unsigned p) { return __uint_as_float(p & 0xffff0000u); }

__device__ __forceinline__ s8 a_from_f32(const float* p) {
    float4 u = *reinterpret_cast<const float4*>(p);
    float4 v = *reinterpret_cast<const float4*>(p + 4);
    s8 r;
    r[0] = (short)bf16r(u.x); r[1] = (short)bf16r(u.y);
    r[2] = (short)bf16r(u.z); r[3] = (short)bf16r(u.w);
    r[4] = (short)bf16r(v.x); r[5] = (short)bf16r(v.y);
    r[6] = (short)bf16r(v.z); r[7] = (short)bf16r(v.w);
    return r;
}

// ======== binA: block-local counting sort by dst>>9; coalesced segment write ========
__global__ __launch_bounds__(256) void k_binA(const int* __restrict__ src,
        const int* __restrict__ dst, int* __restrict__ degcnt,
        int* __restrict__ seg_off, int* __restrict__ seg_cnt,
        unsigned* __restrict__ gseg) {
    __shared__ int cnt[NBKT];
    __shared__ int pre[128];
    __shared__ unsigned sbuf[EPB];
    for (int i = threadIdx.x; i < NBKT; i += 256) cnt[i] = 0;
    __syncthreads();
    int e0 = blockIdx.x * EPB;
    int nE = EE - e0; if (nE > EPB) nE = EPB;
    int b[8]; unsigned val[8]; int rk[8];
    #pragma unroll
    for (int i = 0; i < 8; i++) {
        int li = i * 256 + threadIdx.x;
        if (li < nE) {
            int e = e0 + li;
            int d = dst[e], s = src[e];
            atomicAdd(&degcnt[d], 1);
            b[i] = d >> 9;
            val[i] = ((unsigned)s << 9) | (unsigned)(d & 511);
            rk[i] = atomicAdd(&cnt[b[i]], 1);
        } else b[i] = -1;
    }
    __syncthreads();
    // inclusive Hillis-Steele over 128 (>= NBKT)
    if (threadIdx.x < 128) pre[threadIdx.x] = (threadIdx.x < NBKT) ? cnt[threadIdx.x] : 0;
    __syncthreads();
    for (int off = 1; off < 128; off <<= 1) {
        int v = 0;
        if (threadIdx.x < 128 && threadIdx.x >= off) v = pre[threadIdx.x - off];
        __syncthreads();
        if (threadIdx.x < 128) pre[threadIdx.x] += v;
        __syncthreads();
    }
    #pragma unroll
    for (int i = 0; i < 8; i++)
        if (b[i] >= 0) sbuf[pre[b[i]] - cnt[b[i]] + rk[i]] = val[i];
    if (threadIdx.x < NBKT) {
        seg_off[blockIdx.x * NBKT + threadIdx.x] = pre[threadIdx.x] - cnt[threadIdx.x];
        seg_cnt[blockIdx.x * NBKT + threadIdx.x] = cnt[threadIdx.x];
    }
    __syncthreads();
    for (int i = threadIdx.x; i < nE; i += 256)
        gseg[(size_t)blockIdx.x * EPB + i] = sbuf[i];
}

// ================= scans =================
__global__ void k_scan_a(const int* __restrict__ degcnt, int* __restrict__ bsums) {
    __shared__ int sm[4];
    int i = blockIdx.x * 256 + threadIdx.x;
    int v = (i < NN) ? degcnt[i] : 0;
    #pragma unroll
    for (int o = 1; o < 64; o <<= 1) v += __shfl_xor(v, o, 64);
    if ((threadIdx.x & 63) == 0) sm[threadIdx.x >> 6] = v;
    __syncthreads();
    if (threadIdx.x == 0) bsums[blockIdx.x] = sm[0] + sm[1] + sm[2] + sm[3];
}

__global__ void k_scan_b(const int* __restrict__ bsums, int* __restrict__ bpre) {
    __shared__ int sm[256];
    int t = threadIdx.x;
    sm[t] = (t < NBLK_SCAN) ? bsums[t] : 0;
    __syncthreads();
    for (int off = 1; off < 256; off <<= 1) {
        int u = (t >= off) ? sm[t - off] : 0;
        __syncthreads();
        sm[t] += u;
        __syncthreads();
    }
    if (t < NBLK_SCAN) bpre[t] = (t == 0) ? 0 : sm[t - 1];
}

__global__ void k_scan_c(const int* __restrict__ degcnt, const int* __restrict__ bpre,
                         int* __restrict__ row_start) {
    __shared__ int sm[256];
    int t = threadIdx.x;
    int i = blockIdx.x * 256 + t;
    int v = (i < NN) ? degcnt[i] : 0;
    sm[t] = v;
    __syncthreads();
    for (int off = 1; off < 256; off <<= 1) {
        int u = (t >= off) ? sm[t - off] : 0;
        __syncthreads();
        sm[t] += u;
        __syncthreads();
    }
    int incl = sm[t];
    if (i < NN) row_start[i] = bpre[blockIdx.x] + incl - v;
    if (i == NN - 1) row_start[NN] = bpre[blockIdx.x] + incl;
}

// ======= fused: blocks [0,NBKT) = binB CSR fill (segment gather); rest = projection+GAT-l0 pre =======
__global__ __launch_bounds__(256) void k_binB_pre(
        const int* __restrict__ row_start, const int* __restrict__ seg_off,
        const int* __restrict__ seg_cnt, const unsigned* __restrict__ gseg,
        int* __restrict__ csr_src,
        const float* __restrict__ feat, const int* __restrict__ types,
        const float* __restrict__ Wp, const float* __restrict__ bp,
        const float* __restrict__ Wd, const float* __restrict__ bd,
        const float* __restrict__ gW, const float* __restrict__ al,
        const float* __restrict__ ar,
        float* __restrict__ h0f, unsigned* __restrict__ P,
        float* __restrict__ el, float* __restrict__ er) {
    __shared__ unsigned short WpT[64 * 136];
    __shared__ unsigned short WdT[64 * 72];
    __shared__ unsigned short WgT[64 * 72];
    __shared__ unsigned short y0s[4][16 * 72];
    __shared__ int kur[512];
    if (blockIdx.x < NBKT) {
        int b = blockIdx.x;
        int d0 = b << 9;
        for (int i = threadIdx.x; i < 512; i += 256) {
            int d = d0 + i;
            kur[i] = (d < NN) ? row_start[d] : 0;
        }
        __syncthreads();
        int wv = threadIdx.x >> 6, lane = threadIdx.x & 63;
        for (int seg = wv; seg < NSEG; seg += 4) {
            int off = seg_off[seg * NBKT + b];
            int c = seg_cnt[seg * NBKT + b];
            for (int i = lane; i < c; i += 64) {
                unsigned v = gseg[(size_t)seg * EPB + off + i];
                int p = atomicAdd(&kur[v & 511], 1);
                csr_src[p] = (int)(v >> 9);
            }
        }
        return;
    }
    // ---- projection + GAT-l0 pre (MFMA) ----
    for (int idx = threadIdx.x; idx < 128 * 64; idx += 256) {
        int k = idx >> 6, n = idx & 63;
        WpT[n * 136 + k] = (unsigned short)bf16r(Wp[idx]);
    }
    for (int idx = threadIdx.x; idx < 64 * 64; idx += 256) {
        int k = idx >> 6, n = idx & 63;
        WdT[n * 72 + k] = (unsigned short)bf16r(Wd[idx]);
        WgT[n * 72 + k] = (unsigned short)bf16r(gW[idx]);
    }
    __syncthreads();
    int wv = threadIdx.x >> 6, lane = threadIdx.x & 63;
    int quad = lane >> 4, l16 = lane & 15;
    int gw2 = (blockIdx.x - NBKT) * 4 + wv;
    int mtEnd = gw2 * 2 + 2; if (mtEnd > 3125) mtEnd = 3125;
    for (int mt = gw2 * 2; mt < mtEnd; mt++) {
        int row0 = mt * 16;
        const float* arow = feat + (size_t)(row0 + l16) * 128;
        f4 accp[4], accd[4];
        #pragma unroll
        for (int t = 0; t < 4; t++) { accp[t] = f4{0.f,0.f,0.f,0.f}; accd[t] = f4{0.f,0.f,0.f,0.f}; }
        #pragma unroll
        for (int ks = 0; ks < 4; ks++) {
            s8 a = a_from_f32(arow + ks * 32 + quad * 8);
            #pragma unroll
            for (int t = 0; t < 4; t++) {
                s8 b = *(const s8*)&WpT[(t * 16 + l16) * 136 + ks * 32 + quad * 8];
                accp[t] = __builtin_amdgcn_mfma_f32_16x16x32_bf16(a, b, accp[t], 0, 0, 0);
                if (ks < 2) {
                    s8 bd_ = *(const s8*)&WdT[(t * 16 + l16) * 72 + ks * 32 + quad * 8];
                    accd[t] = __builtin_amdgcn_mfma_f32_16x16x32_bf16(a, bd_, accd[t], 0, 0, 0);
                }
            }
        }
        int ty[4];
        #pragma unroll
        for (int r = 0; r < 4; r++) ty[r] = types[row0 + quad * 4 + r];
        float vv[4][4];
        #pragma unroll
        for (int t = 0; t < 4; t++) {
            int col = t * 16 + l16;
            float bpv = bp[col], bdv = bd[col];
            #pragma unroll
            for (int r = 0; r < 4; r++) {
                float v = ty[r] ? (accd[t][r] + bdv) : (accp[t][r] + bpv);
                vv[t][r] = v;
                h0f[(size_t)(row0 + quad * 4 + r) * 64 + col] = v;
                y0s[wv][(quad * 4 + r) * 72 + col] = (unsigned short)bf16r(v);
            }
        }
        s8 a0 = *(const s8*)&y0s[wv][l16 * 72 + quad * 8];
        s8 a1 = *(const s8*)&y0s[wv][l16 * 72 + 32 + quad * 8];
        f4 hw[4];
        #pragma unroll
        for (int t = 0; t < 4; t++) {
            hw[t] = f4{0.f,0.f,0.f,0.f};
            s8 b0 = *(const s8*)&WgT[(t * 16 + l16) * 72 + quad * 8];
            hw[t] = __builtin_amdgcn_mfma_f32_16x16x32_bf16(a0, b0, hw[t], 0, 0, 0);
            s8 b1_ = *(const s8*)&WgT[(t * 16 + l16) * 72 + 32 + quad * 8];
            hw[t] = __builtin_amdgcn_mfma_f32_16x16x32_bf16(a1, b1_, hw[t], 0, 0, 0);
        }
        #pragma unroll
        for (int t = 0; t < 4; t++) {
            int col = t * 16 + l16;
            float alv = al[col], arv = ar[col];
            #pragma unroll
            for (int r = 0; r < 4; r++) {
                int row = row0 + quad * 4 + r;
                float h = hw[t][r];
                P[(size_t)row * 64 + col] = bf16r(h) | (bf16r(vv[t][r]) << 16);
                float pl = h * alv, pr = h * arv;
                #pragma unroll
                for (int m = 1; m < 16; m <<= 1) {
                    pl += __shfl_xor(pl, m, 64);
                    pr += __shfl_xor(pr, m, 64);
                }
                if (l16 == 0) {
                    el[(size_t)row * 4 + t] = pl;
                    er[(size_t)row * 4 + t] = pr;
                }
            }
        }
    }
}

// ================= edge walk: 1 node/wave, exp once/edge, packed bf16 gather ======
template <int RELU>
__global__ void k_edges(const int* __restrict__ rows, const int* __restrict__ csr,
                        const unsigned* __restrict__ Pin,
                        const float* __restrict__ el, const float* __restrict__ er,
                        const float* __restrict__ gat_in, const float* __restrict__ gin_in,
                        const float* __restrict__ eps_p,
                        float* __restrict__ vgf, unsigned short* __restrict__ vgb,
                        unsigned short* __restrict__ xb) {
    __shared__ float ews[4][256];
    int wv = threadIdx.x >> 6, lane = threadIdx.x & 63;
    int n = blockIdx.x * 4 + wv;
    int st = rows[n], dg = rows[n + 1] - st;
    int hd = lane >> 4;
    float4 erv = *reinterpret_cast<const float4*>(er + (size_t)n * 4);
    float accg = 0.f, acci = 0.f, ssum = 0.f;
    for (int base = 0; base < dg; base += 64) {
        int rem = dg - base; if (rem > 64) rem = 64;
        int myi = 0;
        if (lane < rem) {
            myi = csr[st + base + lane];
            float4 lv = *reinterpret_cast<const float4*>(el + (size_t)myi * 4);
            float4 ev;
            ev.x = __expf(leaky(lv.x + erv.x));
            ev.y = __expf(leaky(lv.y + erv.y));
            ev.z = __expf(leaky(lv.z + erv.z));
            ev.w = __expf(leaky(lv.w + erv.w));
            *reinterpret_cast<float4*>(&ews[wv][lane * 4]) = ev;
        }
        int j = 0;
        for (; j + 4 <= rem; j += 4) {
            int s0 = __shfl(myi, j, 64),     s1 = __shfl(myi, j + 1, 64);
            int s2 = __shfl(myi, j + 2, 64), s3 = __shfl(myi, j + 3, 64);
            unsigned p0 = Pin[(size_t)s0 * 64 + lane];
            unsigned p1 = Pin[(size_t)s1 * 64 + lane];
            unsigned p2 = Pin[(size_t)s2 * 64 + lane];
            unsigned p3 = Pin[(size_t)s3 * 64 + lane];
            float a0 = ews[wv][(j + 0) * 4 + hd];
            float a1 = ews[wv][(j + 1) * 4 + hd];
            float a2 = ews[wv][(j + 2) * 4 + hd];
            float a3 = ews[wv][(j + 3) * 4 + hd];
            accg += a0 * lo16(p0) + a1 * lo16(p1) + a2 * lo16(p2) + a3 * lo16(p3);
            acci += hi16(p0) + hi16(p1) + hi16(p2) + hi16(p3);
            ssum += a0 + a1 + a2 + a3;
        }
        for (; j < rem; j++) {
            int s0 = __shfl(myi, j, 64);
            unsigned p0 = Pin[(size_t)s0 * 64 + lane];
            float a0 = ews[wv][j * 4 + hd];
            accg += a0 * lo16(p0); acci += hi16(p0); ssum += a0;
        }
    }
    float vg = accg / (ssum + 1e-9f) + gat_in[(size_t)n * 64 + lane];
    if (RELU) vg = fmaxf(vg, 0.f);
    float invd = 1.0f / fmaxf((float)dg, 1.0f);
    float x = (1.0f + eps_p[0]) * gin_in[(size_t)n * 64 + lane] + acci * invd;
    size_t off = (size_t)n * 64 + lane;
    vgf[off] = vg;
    vgb[off] = (unsigned short)bf16r(vg);
    xb[off] = (unsigned short)bf16r(x);
}

// ====== k_mlp: GIN MLP (y1 in LDS) + (L==0: GAT-l1 pre | L==1: fused MoE routing) ======
template <int L>
__global__ __launch_bounds__(256) void k_mlp(const unsigned short* __restrict__ Gx,
        const unsigned short* __restrict__ Eb,
        const float* __restrict__ W1, const float* __restrict__ b1,
        const float* __restrict__ W2, const float* __restrict__ b2,
        const float* __restrict__ gatW, const float* __restrict__ al,
        const float* __restrict__ ar,
        unsigned short* __restrict__ Fb, float* __restrict__ Cf,
        unsigned* __restrict__ P, float* __restrict__ el, float* __restrict__ er,
        const float* __restrict__ Zg, const float* __restrict__ ggW,
        const float* __restrict__ ggb, const float* __restrict__ igW,
        const float* __restrict__ igb,
        float* __restrict__ wgtg, float* __restrict__ wgti,
        float* __restrict__ stats) {
    __shared__ unsigned short W1T[64 * 72];
    __shared__ unsigned short W2T[64 * 72];
    __shared__ unsigned short WgT[(L == 0) ? 64 * 72 : 64];
    __shared__ unsigned short y1s[4][16 * 72];
    __shared__ float sstat[16];
    if (L == 1 && threadIdx.x < 16) sstat[threadIdx.x] = 0.f;
    for (int idx = threadIdx.x; idx < 64 * 64; idx += 256) {
        int k = idx >> 6, n = idx & 63;
        W1T[n * 72 + k] = (unsigned short)bf16r(W1[idx]);
        W2T[n * 72 + k] = (unsigned short)bf16r(W2[idx]);
        if (L == 0) WgT[n * 72 + k] = (unsigned short)bf16r(gatW[idx]);
    }
    __syncthreads();
    int wv = threadIdx.x >> 6, lane = threadIdx.x & 63;
    int quad = lane >> 4, l16 = lane & 15;
    int gw = blockIdx.x * 4 + wv;
    int mtEnd = gw * 2 + 2; if (mtEnd > 3125) mtEnd = 3125;
    float sp[2][4] = {{0,0,0,0},{0,0,0,0}};
    float sh[2][4] = {{0,0,0,0},{0,0,0,0}};
    for (int mt = gw * 2; mt < mtEnd; mt++) {
        int row0 = mt * 16;
        const unsigned short* arow = Gx + (size_t)(row0 + l16) * 64;
        s8 a0 = *(const s8*)(arow + quad * 8);
        s8 a1 = *(const s8*)(arow + 32 + quad * 8);
        f4 acc1[4];
        #pragma unroll
        for (int t = 0; t < 4; t++) {
            acc1[t] = f4{0.f,0.f,0.f,0.f};
            s8 b0 = *(const s8*)&W1T[(t * 16 + l16) * 72 + quad * 8];
            acc1[t] = __builtin_amdgcn_mfma_f32_16x16x32_bf16(a0, b0, acc1[t], 0, 0, 0);
            s8 b1_ = *(const s8*)&W1T[(t * 16 + l16) * 72 + 32 + quad * 8];
            acc1[t] = __builtin_amdgcn_mfma_f32_16x16x32_bf16(a1, b1_, acc1[t], 0, 0, 0);
        }
        #pragma unroll
        for (int t = 0; t < 4; t++) {
            float b1v = b1[t * 16 + l16];
            #pragma unroll
            for (int r = 0; r < 4; r++) {
                float v = fmaxf(acc1[t][r] + b1v, 0.f);
                y1s[wv][(quad * 4 + r) * 72 + t * 16 + l16] = (unsigned short)bf16r(v);
            }
        }
        s8 c0 = *(const s8*)&y1s[wv][l16 * 72 + quad * 8];
        s8 c1 = *(const s8*)&y1s[wv][l16 * 72 + 32 + quad * 8];
        f4 acc2[4];
        #pragma unroll
        for (int t = 0; t < 4; t++) {
            acc2[t] = f4{0.f,0.f,0.f,0.f};
            s8 b0 = *(const s8*)&W2T[(t * 16 + l16) * 72 + quad * 8];
            acc2[t] = __builtin_amdgcn_mfma_f32_16x16x32_bf16(c0, b0, acc2[t], 0, 0, 0);
            s8 b1_ = *(const s8*)&W2T[(t * 16 + l16) * 72 + 32 + quad * 8];
            acc2[t] = __builtin_amdgcn_mfma_f32_16x16x32_bf16(c1, b1_, acc2[t], 0, 0, 0);
        }
        unsigned short vb[4][4];
        float vout[4][4];
        #pragma unroll
        for (int t = 0; t < 4; t++) {
            int col = t * 16 + l16;
            float b2v = b2[col];
            #pragma unroll
            for (int r = 0; r < 4; r++) {
                float v = acc2[t][r] + b2v;
                if (L == 0) v = fmaxf(v, 0.f);
                size_t off = (size_t)(row0 + quad * 4 + r) * 64 + col;
                unsigned short vb16 = (unsigned short)bf16r(v);
                vb[t][r] = vb16;
                vout[t][r] = v;
                Fb[off] = vb16;
                if (L == 0) Cf[off] = v;
            }
        }
        if (L == 0) {
            const unsigned short* erow = Eb + (size_t)(row0 + l16) * 64;
            s8 e0 = *(const s8*)(erow + quad * 8);
            s8 e1 = *(const s8*)(erow + 32 + quad * 8);
            f4 hw[4];
            #pragma unroll
            for (int t = 0; t < 4; t++) {
                hw[t] = f4{0.f,0.f,0.f,0.f};
                s8 b0 = *(const s8*)&WgT[(t * 16 + l16) * 72 + quad * 8];
                hw[t] = __builtin_amdgcn_mfma_f32_16x16x32_bf16(e0, b0, hw[t], 0, 0, 0);
                s8 b1_ = *(const s8*)&WgT[(t * 16 + l16) * 72 + 32 + quad * 8];
                hw[t] = __builtin_amdgcn_mfma_f32_16x16x32_bf16(e1, b1_, hw[t], 0, 0, 0);
            }
            #pragma unroll
            for (int t = 0; t < 4; t++) {
                int col = t * 16 + l16;
                float alv = al[col], arv = ar[col];
                #pragma unroll
                for (int r = 0; r < 4; r++) {
                    int row = row0 + quad * 4 + r;
                    float h = hw[t][r];
                    P[(size_t)row * 64 + col] = bf16r(h) | ((unsigned)vb[t][r] << 16);
                    float pl = h * alv, pr = h * arv;
                    #pragma unroll
                    for (int m = 1; m < 16; m <<= 1) {
                        pl += __shfl_xor(pl, m, 64);
                        pr += __shfl_xor(pr, m, 64);
                    }
                    if (l16 == 0) {
                        el[(size_t)row * 4 + t] = pl;
                        er[(size_t)row * 4 + t] = pr;
                    }
                }
            }
        } else {
            // fused MoE routing: zg from global (B), zi from registers
            #pragma unroll
            for (int r = 0; r < 4; r++) {
                int row = row0 + quad * 4 + r;
                float pg[4] = {0,0,0,0}, pi[4] = {0,0,0,0};
                #pragma unroll
                for (int t = 0; t < 4; t++) {
                    int col = t * 16 + l16;
                    float zgv = Zg[(size_t)row * 64 + col];
                    float ziv = vout[t][r];
                    #pragma unroll
                    for (int e = 0; e < 4; e++) {
                        pg[e] += zgv * ggW[col * 4 + e];
                        pi[e] += ziv * igW[col * 4 + e];
                    }
                }
                #pragma unroll
                for (int m = 1; m < 16; m <<= 1) {
                    #pragma unroll
                    for (int e = 0; e < 4; e++) {
                        pg[e] += __shfl_xor(pg[e], m, 64);
                        pi[e] += __shfl_xor(pi[e], m, 64);
                    }
                }
                if (l16 == 0) {
                    #pragma unroll
                    for (int q = 0; q < 2; q++) {
                        float lg0 = (q ? pi[0] + igb[0] : pg[0] + ggb[0]);
                        float lg1 = (q ? pi[1] + igb[1] : pg[1] + ggb[1]);
                        float lg2 = (q ? pi[2] + igb[2] : pg[2] + ggb[2]);
                        float lg3 = (q ? pi[3] + igb[3] : pg[3] + ggb[3]);
                        float mx = fmaxf(fmaxf(lg0, lg1), fmaxf(lg2, lg3));
                        float ex0 = __expf(lg0 - mx), ex1 = __expf(lg1 - mx);
                        float ex2 = __expf(lg2 - mx), ex3 = __expf(lg3 - mx);
                        float inv = 1.0f / (ex0 + ex1 + ex2 + ex3);
                        float pr4[4] = {ex0 * inv, ex1 * inv, ex2 * inv, ex3 * inv};
                        int i1 = 0; float v1 = pr4[0];
                        #pragma unroll
                        for (int t = 1; t < 4; t++) if (pr4[t] > v1) { v1 = pr4[t]; i1 = t; }
                        int i2 = -1; float v2 = -1.f;
                        #pragma unroll
                        for (int t = 0; t < 4; t++) if (t != i1 && pr4[t] > v2) { v2 = pr4[t]; i2 = t; }
                        float wsum = v1 + v2;
                        float wq[4] = {0.f, 0.f, 0.f, 0.f};
                        wq[i1] = v1 / wsum; wq[i2] = v2 / wsum;
                        float* WD = q ? wgti : wgtg;
                        *reinterpret_cast<float4*>(WD + (size_t)row * 4) =
                            float4{wq[0], wq[1], wq[2], wq[3]};
                        #pragma unroll
                        for (int t = 0; t < 4; t++) sp[q][t] += pr4[t];
                        sh[q][i1] += 1.f; sh[q][i2] += 1.f;
                    }
                }
            }
        }
    }
    if (L == 1) {
        __syncthreads();
        if (l16 == 0) {
            #pragma unroll
            for (int q = 0; q < 2; q++)
                #pragma unroll
                for (int e = 0; e < 4; e++) {
                    atomicAdd(&sstat[q * 8 + e], sp[q][e]);
                    atomicAdd(&sstat[q * 8 + 4 + e], sh[q][e]);
                }
        }
        __syncthreads();
        if (threadIdx.x < 16) atomicAdd(&stats[threadIdx.x], sstat[threadIdx.x]);
    }
}

// ======= dense-all experts (MFMA), both problems in one grid =======
__global__ __launch_bounds__(256) void k_expert(const unsigned short* __restrict__ Eb,
        const unsigned short* __restrict__ Fb,
        const float* __restrict__ g_eW1, const float* __restrict__ g_eb1,
        const float* __restrict__ g_eW2, const float* __restrict__ g_eb2,
        const float* __restrict__ i_eW1, const float* __restrict__ i_eb1,
        const float* __restrict__ i_eW2, const float* __restrict__ i_eb2,
        const float* __restrict__ wgtg, const float* __restrict__ wgti,
        float* __restrict__ moegf, float* __restrict__ moeif,
        unsigned short* __restrict__ ub) {
    __shared__ unsigned short w1t[4 * 32 * 72];
    __shared__ unsigned short w2t[4 * 64 * 40];
    __shared__ unsigned short y1s[4][16 * 40];
    int p = (blockIdx.x >= NBE) ? 1 : 0;
    int bb = blockIdx.x - p * NBE;
    const unsigned short* Ab = p ? Fb : Eb;
    const float* eW1 = p ? i_eW1 : g_eW1;
    const float* eb1 = p ? i_eb1 : g_eb1;
    const float* eW2 = p ? i_eW2 : g_eW2;
    const float* eb2 = p ? i_eb2 : g_eb2;
    const float* wgt = p ? wgti : wgtg;
    float* moef = p ? moeif : moegf;
    int qoff = p ? 64 : 0;
    for (int g = threadIdx.x; g < 8192; g += 256) {
        int e = g >> 11, rem = g & 2047;
        int k = rem >> 5, n = rem & 31;
        w1t[e * 2304 + n * 72 + k] = (unsigned short)bf16r(eW1[g]);
    }
    for (int g = threadIdx.x; g < 8192; g += 256) {
        int e = g >> 11, rem = g & 2047;
        int k = rem >> 6, n = rem & 63;
        w2t[e * 2560 + n * 40 + k] = (unsigned short)bf16r(eW2[g]);
    }
    __syncthreads();
    int wv = threadIdx.x >> 6, lane = threadIdx.x & 63;
    int quad = lane >> 4, l16 = lane & 15;
    int gw = bb * 4 + wv;
    int mtEnd = gw * 4 + 4; if (mtEnd > 3125) mtEnd = 3125;
    for (int mt = gw * 4; mt < mtEnd; mt++) {
        int row0 = mt * 16;
        const unsigned short* arow = Ab + (size_t)(row0 + l16) * 64;
        s8 a0 = *(const s8*)(arow + quad * 8);
        s8 a1 = *(const s8*)(arow + 32 + quad * 8);
        f4 outacc[4];
        #pragma unroll
        for (int t = 0; t < 4; t++) outacc[t] = f4{0.f,0.f,0.f,0.f};
        for (int e = 0; e < 4; e++) {
            f4 acc1[2];
            #pragma unroll
            for (int t = 0; t < 2; t++) {
                acc1[t] = f4{0.f,0.f,0.f,0.f};
                s8 b0 = *(const s8*)&w1t[e * 2304 + (t * 16 + l16) * 72 + quad * 8];
                acc1[t] = __builtin_amdgcn_mfma_f32_16x16x32_bf16(a0, b0, acc1[t], 0, 0, 0);
                s8 b1_ = *(const s8*)&w1t[e * 2304 + (t * 16 + l16) * 72 + 32 + quad * 8];
                acc1[t] = __builtin_amdgcn_mfma_f32_16x16x32_bf16(a1, b1_, acc1[t], 0, 0, 0);
            }
            #pragma unroll
            for (int t = 0; t < 2; t++) {
                float b1v = eb1[e * 32 + t * 16 + l16];
                #pragma unroll
                for (int r = 0; r < 4; r++) {
                    float v = fmaxf(acc1[t][r] + b1v, 0.f);
                    y1s[wv][(quad * 4 + r) * 40 + t * 16 + l16] = (unsigned short)bf16r(v);
                }
            }
            s8 a2 = *(const s8*)&y1s[wv][l16 * 40 + quad * 8];
            f4 acc2[4];
            #pragma unroll
            for (int t = 0; t < 4; t++) {
                acc2[t] = f4{0.f,0.f,0.f,0.f};
                s8 b2_ = *(const s8*)&w2t[e * 2560 + (t * 16 + l16) * 40 + quad * 8];
                acc2[t] = __builtin_amdgcn_mfma_f32_16x16x32_bf16(a2, b2_, acc2[t], 0, 0, 0);
            }
            #pragma unroll
            for (int t = 0; t < 4; t++) {
                float b2v = eb2[e * 64 + t * 16 + l16];
                #pragma unroll
                for (int r = 0; r < 4; r++) {
                    float we = wgt[(size_t)(row0 + quad * 4 + r) * 4 + e];
                    outacc[t][r] += we * (acc2[t][r] + b2v);
                }
            }
        }
        #pragma unroll
        for (int t = 0; t < 4; t++) {
            int col = t * 16 + l16;
            #pragma unroll
            for (int r = 0; r < 4; r++) {
                int row = row0 + quad * 4 + r;
                float v = outacc[t][r];
                moef[(size_t)row * 64 + col] = v;
                ub[(size_t)row * 128 + qoff + col] = (unsigned short)bf16r(v);
            }
        }
    }
}

// ================= fusion gate (MFMA) + aux finalize (block 0) =================
__global__ __launch_bounds__(256) void k_fusion(const unsigned short* __restrict__ ubuf,
        const float* __restrict__ W1, const float* __restrict__ b1,
        const float* __restrict__ W2, const float* __restrict__ b2,
        const float* __restrict__ moegf, const float* __restrict__ moeif,
        float* __restrict__ out, const float* __restrict__ stats) {
    __shared__ unsigned short W1T[64 * 136];
    __shared__ unsigned short W2T[64 * 72];
    __shared__ unsigned short y1s[4][16 * 72];
    for (int idx = threadIdx.x; idx < 128 * 64; idx += 256) {
        int k = idx >> 6, n = idx & 63;
        W1T[n * 136 + k] = (unsigned short)bf16r(W1[idx]);
    }
    for (int idx = threadIdx.x; idx < 64 * 64; idx += 256) {
        int k = idx >> 6, n = idx & 63;
        W2T[n * 72 + k] = (unsigned short)bf16r(W2[idx]);
    }
    __syncthreads();
    int wv = threadIdx.x >> 6, lane = threadIdx.x & 63;
    int quad = lane >> 4, l16 = lane & 15;
    int gw = blockIdx.x * 4 + wv;
    int mtEnd = gw * 2 + 2; if (mtEnd > 3125) mtEnd = 3125;
    for (int mt = gw * 2; mt < mtEnd; mt++) {
        int row0 = mt * 16;
        const unsigned short* arow = ubuf + (size_t)(row0 + l16) * 128;
        f4 acc1[4];
        #pragma unroll
        for (int t = 0; t < 4; t++) acc1[t] = f4{0.f,0.f,0.f,0.f};
        #pragma unroll
        for (int ks = 0; ks < 4; ks++) {
            s8 a = *(const s8*)(arow + ks * 32 + quad * 8);
            #pragma unroll
            for (int t = 0; t < 4; t++) {
                s8 b = *(const s8*)&W1T[(t * 16 + l16) * 136 + ks * 32 + quad * 8];
                acc1[t] = __builtin_amdgcn_mfma_f32_16x16x32_bf16(a, b, acc1[t], 0, 0, 0);
            }
        }
        #pragma unroll
        for (int t = 0; t < 4; t++) {
            float b1v = b1[t * 16 + l16];
            #pragma unroll
            for (int r = 0; r < 4; r++) {
                float v = fmaxf(acc1[t][r] + b1v, 0.f);
                y1s[wv][(quad * 4 + r) * 72 + t * 16 + l16] = (unsigned short)bf16r(v);
            }
        }
        f4 acc2[4];
        #pragma unroll
        for (int t = 0; t < 4; t++) acc2[t] = f4{0.f,0.f,0.f,0.f};
        #pragma unroll
        for (int ks = 0; ks < 2; ks++) {
            s8 a = *(const s8*)&y1s[wv][l16 * 72 + ks * 32 + quad * 8];
            #pragma unroll
            for (int t = 0; t < 4; t++) {
                s8 b = *(const s8*)&W2T[(t * 16 + l16) * 72 + ks * 32 + quad * 8];
                acc2[t] = __builtin_amdgcn_mfma_f32_16x16x32_bf16(a, b, acc2[t], 0, 0, 0);
            }
        }
        #pragma unroll
        for (int t = 0; t < 4; t++) {
            int col = t * 16 + l16;
            float b2v = b2[col];
            #pragma unroll
            for (int r = 0; r < 4; r++) {
                int row = row0 + quad * 4 + r;
                float g = 1.0f / (1.0f + __expf(-(acc2[t][r] + b2v)));
                float zgv = moegf[(size_t)row * 64 + col];
                float ziv = moeif[(size_t)row * 64 + col];
                out[(size_t)row * 64 + col] = g * zgv * ziv + (1.0f - g) * g;
            }
        }
    }
    if (blockIdx.x == 0 && threadIdx.x < 64) {
        int t = threadIdx.x;
        float s = (t < 16) ? stats[t] : 0.f;
        float aux = 0.f;
        for (int q = 0; q < 2; q++) {
            float a = 0.f;
            for (int e = 0; e < 4; e++) {
                float pr = __shfl(s, q * 8 + e, 64);
                float f  = __shfl(s, q * 8 + 4 + e, 64);
                a += (f / (float)NN) * (pr / (float)NN);
            }
            aux += 4.0f * a;
        }
        if (t == 0) out[(size_t)NN * 64] = aux;
    }
}

extern "C" void kernel_launch(void* const* d_in, const int* in_sizes, int n_in,
                              void* d_out, int out_size, void* d_ws, size_t ws_size,
                              hipStream_t stream) {
    (void)in_sizes; (void)n_in; (void)out_size; (void)ws_size;
    const float* features  = (const float*)d_in[0];
    const int*   node_types= (const int*)d_in[1];
    const int*   src       = (const int*)d_in[2];
    const int*   dst       = (const int*)d_in[3];
    const float* W_person  = (const float*)d_in[4];
    const float* b_person  = (const float*)d_in[5];
    const float* W_disease = (const float*)d_in[6];
    const float* b_disease = (const float*)d_in[7];
    const float* gat_W     = (const float*)d_in[8];
    const float* gat_al    = (const float*)d_in[9];
    const float* gat_ar    = (const float*)d_in[10];
    const float* gin_eps   = (const float*)d_in[11];
    const float* gin_W1    = (const float*)d_in[12];
    const float* gin_b1    = (const float*)d_in[13];
    const float* gin_W2    = (const float*)d_in[14];
    const float* gin_b2    = (const float*)d_in[15];
    const float* gat_gW    = (const float*)d_in[16];
    const float* gat_gb    = (const float*)d_in[17];
    const float* gat_eW1   = (const float*)d_in[18];
    const float* gat_eb1   = (const float*)d_in[19];
    const float* gat_eW2   = (const float*)d_in[20];
    const float* gat_eb2   = (const float*)d_in[21];
    const float* gin_gW    = (const float*)d_in[22];
    const float* gin_gb    = (const float*)d_in[23];
    const float* gin_eW1   = (const float*)d_in[24];
    const float* gin_eb1   = (const float*)d_in[25];
    const float* gin_eW2   = (const float*)d_in[26];
    const float* gin_eb2   = (const float*)d_in[27];
    const float* fg_W1     = (const float*)d_in[28];
    const float* fg_b1     = (const float*)d_in[29];
    const float* fg_W2     = (const float*)d_in[30];
    const float* fg_b2     = (const float*)d_in[31];
    float* out = (float*)d_out;

    float* ws = (float*)d_ws;
    size_t o = 0;
    float* A = ws + o; o += (size_t)NN * 64;        // h0f; later ub (bf16 NN x 128)
    float* B = ws + o; o += (size_t)NN * 64;        // vg f32 chain; later moegf
    float* C = ws + o; o += (size_t)NN * 64;        // gin l0 f32; later moeif
    unsigned short* E  = (unsigned short*)(ws + o); o += (size_t)NN * 32;  // vgb
    unsigned short* F  = (unsigned short*)(ws + o); o += (size_t)NN * 32;  // ginb
    unsigned short* G  = (unsigned short*)(ws + o); o += (size_t)NN * 32;  // xb
    unsigned* P = (unsigned*)(ws + o); o += (size_t)NN * 64;  // packed hW|gin
    float* el = ws + o; o += (size_t)NN * 4;
    float* er = ws + o; o += (size_t)NN * 4;
    float* wgtg = ws + o; o += (size_t)NN * 4;
    float* wgti = ws + o; o += (size_t)NN * 4;
    // zeroed region: degcnt | stats (single memset)
    int* degcnt    = (int*)(ws + o); o += NN;
    float* stats   = ws + o; o += 16;
    int* row_start = (int*)(ws + o); o += NN + 4;
    int* bsums     = (int*)(ws + o); o += 256;
    int* bpre      = (int*)(ws + o); o += 256;
    int* csr_src   = (int*)(ws + o); o += EE;
    int* seg_off   = (int*)(ws + o); o += NSEG * NBKT + 64;
    int* seg_cnt   = (int*)(ws + o); o += NSEG * NBKT + 64;
    unsigned* gseg = (unsigned*)(ws + o); o += (size_t)NSEG * EPB;

    unsigned short* ub = (unsigned short*)A;  // reuse after edges(l0)

    const int NB_node = NN / 4;     // 12500

    hipMemsetAsync(degcnt, 0, sizeof(int) * NN + sizeof(float) * 16, stream);

    // CSR build: block-local counting sort, scans
    k_binA<<<NSEG, 256, 0, stream>>>(src, dst, degcnt, seg_off, seg_cnt, gseg);
    k_scan_a<<<NBLK_SCAN, 256, 0, stream>>>(degcnt, bsums);
    k_scan_b<<<1, 256, 0, stream>>>(bsums, bpre);
    k_scan_c<<<NBLK_SCAN, 256, 0, stream>>>(degcnt, bpre, row_start);

    // fused: CSR fill (blocks 0..97, segment gather) + projection/GAT-l0 pre
    k_binB_pre<<<NBKT + NBG, 256, 0, stream>>>(row_start, seg_off, seg_cnt, gseg, csr_src,
                                               features, node_types, W_person, b_person,
                                               W_disease, b_disease, gat_W, gat_al, gat_ar,
                                               A, P, el, er);

    // ---- layer 0 ----
    k_edges<1><<<NB_node, 256, 0, stream>>>(row_start, csr_src, P, el, er, A, A,
                                            gin_eps, B, E, G);
    k_mlp<0><<<NBG, 256, 0, stream>>>(G, E, gin_W1, gin_b1, gin_W2, gin_b2,
                                      gat_W + 4096, gat_al + 64, gat_ar + 64,
                                      F, C, P, el, er,
                                      nullptr, nullptr, nullptr, nullptr, nullptr,
                                      nullptr, nullptr, nullptr);

    // ---- layer 1 (+fused MoE routing) ----
    k_edges<0><<<NB_node, 256, 0, stream>>>(row_start, csr_src, P, el, er, B, C,
                                            gin_eps + 1, B, E, G);
    k_mlp<1><<<NBG, 256, 0, stream>>>(G, nullptr, gin_W1 + 4096, gin_b1 + 64,
                                      gin_W2 + 4096, gin_b2 + 64,
                                      nullptr, nullptr, nullptr,
                                      F, nullptr, nullptr, nullptr, nullptr,
                                      B, gat_gW, gat_gb, gin_gW, gin_gb,
                                      wgtg, wgti, stats);

    // ---- dense-all experts ----
    k_expert<<<NBE * 2, 256, 0, stream>>>(E, F,
                                          gat_eW1, gat_eb1, gat_eW2, gat_eb2,
                                          gin_eW1, gin_eb1, gin_eW2, gin_eb2,
                                          wgtg, wgti, B, C, ub);

    // ---- fusion + aux ----
    k_fusion<<<NBG, 256, 0, stream>>>(ub, fg_W1, fg_b1, fg_W2, fg_b2, B, C, out, stats);
}

// Round 10
// 352.772 us; speedup vs baseline: 1.1375x; 1.1375x over previous
//
#include <hip/hip_runtime.h>

#define NN 50000
#define EE 800000
#define NEG 0.2f
#define NBLK_SCAN 196   // ceil(NN/256)
#define NBG 391         // gemm grid: 1564 waves x 2 mtiles >= 3125
#define NBE 196         // expert grid: 784 waves x 4 mtiles >= 3125
#define NBKT 98         // dst buckets of 512
#define EPB 4096        // edges per binA block
#define NSEG 196        // ceil(EE/EPB)

typedef __attribute__((ext_vector_type(8))) short s8;
typedef __attribute__((ext_vector_type(4))) float f4;

__device__ __forceinline__ float leaky(float x) { return x > 0.f ? x : NEG * x; }
__device__ __forceinline__ unsigned bf16r(float x) {
    unsigned u = __float_as_uint(x);
    return (u + 0x7fffu + ((u >> 16) & 1u)) >> 16;
}
__device__ __forceinline__ float lo16(unsigned p) { return __uint_as_float(p << 16); }
__device__ __forceinline__ float hi16(unsigned p) { return __uint_as_float(p & 0xffff0000u); }

__device__ __forceinline__ s8 a_from_f32(const float* p) {
    float4 u = *reinterpret_cast<const float4*>(p);
    float4 v = *reinterpret_cast<const float4*>(p + 4);
    s8 r;
    r[0] = (short)bf16r(u.x); r[1] = (short)bf16r(u.y);
    r[2] = (short)bf16r(u.z); r[3] = (short)bf16r(u.w);
    r[4] = (short)bf16r(v.x); r[5] = (short)bf16r(v.y);
    r[6] = (short)bf16r(v.z); r[7] = (short)bf16r(v.w);
    return r;
}

// ======== binA: block-local counting sort by dst>>9; coalesced segment write ========
__global__ __launch_bounds__(256) void k_binA(const int* __restrict__ src,
        const int* __restrict__ dst, int* __restrict__ degcnt,
        int* __restrict__ seg_off, int* __restrict__ seg_cnt,
        unsigned* __restrict__ gseg) {
    __shared__ int cnt[NBKT];
    __shared__ int pre[128];
    __shared__ unsigned sbuf[EPB];
    for (int i = threadIdx.x; i < NBKT; i += 256) cnt[i] = 0;
    __syncthreads();
    int e0 = blockIdx.x * EPB;
    int nE = EE - e0; if (nE > EPB) nE = EPB;
    int b[16]; unsigned val[16]; int rk[16];
    #pragma unroll
    for (int i = 0; i < 16; i++) {
        int li = i * 256 + threadIdx.x;
        if (li < nE) {
            int e = e0 + li;
            int d = dst[e], s = src[e];
            atomicAdd(&degcnt[d], 1);
            b[i] = d >> 9;
            val[i] = ((unsigned)s << 9) | (unsigned)(d & 511);
            rk[i] = atomicAdd(&cnt[b[i]], 1);
        } else b[i] = -1;
    }
    __syncthreads();
    // inclusive Hillis-Steele over 128 (>= NBKT)
    if (threadIdx.x < 128) pre[threadIdx.x] = (threadIdx.x < NBKT) ? cnt[threadIdx.x] : 0;
    __syncthreads();
    for (int off = 1; off < 128; off <<= 1) {
        int v = 0;
        if (threadIdx.x < 128 && threadIdx.x >= off) v = pre[threadIdx.x - off];
        __syncthreads();
        if (threadIdx.x < 128) pre[threadIdx.x] += v;
        __syncthreads();
    }
    #pragma unroll
    for (int i = 0; i < 16; i++)
        if (b[i] >= 0) sbuf[pre[b[i]] - cnt[b[i]] + rk[i]] = val[i];
    if (threadIdx.x < NBKT) {
        seg_off[blockIdx.x * NBKT + threadIdx.x] = pre[threadIdx.x] - cnt[threadIdx.x];
        seg_cnt[blockIdx.x * NBKT + threadIdx.x] = cnt[threadIdx.x];
    }
    __syncthreads();
    for (int i = threadIdx.x; i < nE; i += 256)
        gseg[(size_t)blockIdx.x * EPB + i] = sbuf[i];
}

// ================= scans =================
__global__ void k_scan_a(const int* __restrict__ degcnt, int* __restrict__ bsums) {
    __shared__ int sm[4];
    int i = blockIdx.x * 256 + threadIdx.x;
    int v = (i < NN) ? degcnt[i] : 0;
    #pragma unroll
    for (int o = 1; o < 64; o <<= 1) v += __shfl_xor(v, o, 64);
    if ((threadIdx.x & 63) == 0) sm[threadIdx.x >> 6] = v;
    __syncthreads();
    if (threadIdx.x == 0) bsums[blockIdx.x] = sm[0] + sm[1] + sm[2] + sm[3];
}

__global__ void k_scan_b(const int* __restrict__ bsums, int* __restrict__ bpre) {
    __shared__ int sm[256];
    int t = threadIdx.x;
    sm[t] = (t < NBLK_SCAN) ? bsums[t] : 0;
    __syncthreads();
    for (int off = 1; off < 256; off <<= 1) {
        int u = (t >= off) ? sm[t - off] : 0;
        __syncthreads();
        sm[t] += u;
        __syncthreads();
    }
    if (t < NBLK_SCAN) bpre[t] = (t == 0) ? 0 : sm[t - 1];
}

__global__ void k_scan_c(const int* __restrict__ degcnt, const int* __restrict__ bpre,
                         int* __restrict__ row_start) {
    __shared__ int sm[256];
    int t = threadIdx.x;
    int i = blockIdx.x * 256 + t;
    int v = (i < NN) ? degcnt[i] : 0;
    sm[t] = v;
    __syncthreads();
    for (int off = 1; off < 256; off <<= 1) {
        int u = (t >= off) ? sm[t - off] : 0;
        __syncthreads();
        sm[t] += u;
        __syncthreads();
    }
    int incl = sm[t];
    if (i < NN) row_start[i] = bpre[blockIdx.x] + incl - v;
    if (i == NN - 1) row_start[NN] = bpre[blockIdx.x] + incl;
}

// ======= fused: blocks [0,NBKT) = binB CSR fill (parallel binary-search gather);
//         blocks [NBKT,..) = projection + GAT-l0 pre =======
__global__ __launch_bounds__(256) void k_binB_pre(
        const int* __restrict__ row_start, const int* __restrict__ seg_off,
        const int* __restrict__ seg_cnt, const unsigned* __restrict__ gseg,
        int* __restrict__ csr_src,
        const float* __restrict__ feat, const int* __restrict__ types,
        const float* __restrict__ Wp, const float* __restrict__ bp,
        const float* __restrict__ Wd, const float* __restrict__ bd,
        const float* __restrict__ gW, const float* __restrict__ al,
        const float* __restrict__ ar,
        float* __restrict__ h0f, unsigned* __restrict__ P,
        float* __restrict__ el, float* __restrict__ er) {
    __shared__ unsigned short WpT[64 * 136];
    __shared__ unsigned short WdT[64 * 72];
    __shared__ unsigned short WgT[64 * 72];
    __shared__ unsigned short y0s[4][16 * 72];
    __shared__ int kur[512];
    if (blockIdx.x < NBKT) {
        // ---- binB: parallel gather via bucket-local prefix + binary search ----
        int b = blockIdx.x;
        int t = threadIdx.x;
        int* spre = (int*)WpT;   // NSEG+1 ints (aliases weight LDS, unused here)
        int* soff = (int*)WdT;   // NSEG ints
        int* ss   = (int*)WgT;   // 256 ints
        int c0 = (2 * t     < NSEG) ? seg_cnt[(2 * t)     * NBKT + b] : 0;
        int c1 = (2 * t + 1 < NSEG) ? seg_cnt[(2 * t + 1) * NBKT + b] : 0;
        if (2 * t     < NSEG) soff[2 * t]     = seg_off[(2 * t)     * NBKT + b];
        if (2 * t + 1 < NSEG) soff[2 * t + 1] = seg_off[(2 * t + 1) * NBKT + b];
        ss[t] = c0 + c1;
        __syncthreads();
        for (int off = 1; off < 256; off <<= 1) {
            int u = (t >= off) ? ss[t - off] : 0;
            __syncthreads();
            ss[t] += u;
            __syncthreads();
        }
        int base = ss[t] - (c0 + c1);
        if (2 * t     < NSEG) spre[2 * t]     = base;
        if (2 * t + 1 < NSEG) spre[2 * t + 1] = base + c0;
        if (t == 0) spre[NSEG] = ss[255];
        int d0 = b << 9;
        for (int i = t; i < 512; i += 256) {
            int d = d0 + i;
            kur[i] = (d < NN) ? row_start[d] : 0;
        }
        __syncthreads();
        int cntb = spre[NSEG];
        for (int idx = t; idx < cntb; idx += 256) {
            int lo = 0, hi = NSEG - 1;
            #pragma unroll
            for (int s = 0; s < 8; s++) {   // 2^8 = 256 >= NSEG
                int mid = (lo + hi + 1) >> 1;
                if (spre[mid] <= idx) lo = mid; else hi = mid - 1;
            }
            unsigned v = gseg[(size_t)lo * EPB + soff[lo] + (idx - spre[lo])];
            int p = atomicAdd(&kur[v & 511], 1);
            csr_src[p] = (int)(v >> 9);
        }
        return;
    }
    // ---- projection + GAT-l0 pre (MFMA) ----
    for (int idx = threadIdx.x; idx < 128 * 64; idx += 256) {
        int k = idx >> 6, n = idx & 63;
        WpT[n * 136 + k] = (unsigned short)bf16r(Wp[idx]);
    }
    for (int idx = threadIdx.x; idx < 64 * 64; idx += 256) {
        int k = idx >> 6, n = idx & 63;
        WdT[n * 72 + k] = (unsigned short)bf16r(Wd[idx]);
        WgT[n * 72 + k] = (unsigned short)bf16r(gW[idx]);
    }
    __syncthreads();
    int wv = threadIdx.x >> 6, lane = threadIdx.x & 63;
    int quad = lane >> 4, l16 = lane & 15;
    int gw2 = (blockIdx.x - NBKT) * 4 + wv;
    int mtEnd = gw2 * 2 + 2; if (mtEnd > 3125) mtEnd = 3125;
    for (int mt = gw2 * 2; mt < mtEnd; mt++) {
        int row0 = mt * 16;
        const float* arow = feat + (size_t)(row0 + l16) * 128;
        f4 accp[4], accd[4];
        #pragma unroll
        for (int t = 0; t < 4; t++) { accp[t] = f4{0.f,0.f,0.f,0.f}; accd[t] = f4{0.f,0.f,0.f,0.f}; }
        #pragma unroll
        for (int ks = 0; ks < 4; ks++) {
            s8 a = a_from_f32(arow + ks * 32 + quad * 8);
            #pragma unroll
            for (int t = 0; t < 4; t++) {
                s8 b = *(const s8*)&WpT[(t * 16 + l16) * 136 + ks * 32 + quad * 8];
                accp[t] = __builtin_amdgcn_mfma_f32_16x16x32_bf16(a, b, accp[t], 0, 0, 0);
                if (ks < 2) {
                    s8 bd_ = *(const s8*)&WdT[(t * 16 + l16) * 72 + ks * 32 + quad * 8];
                    accd[t] = __builtin_amdgcn_mfma_f32_16x16x32_bf16(a, bd_, accd[t], 0, 0, 0);
                }
            }
        }
        int ty[4];
        #pragma unroll
        for (int r = 0; r < 4; r++) ty[r] = types[row0 + quad * 4 + r];
        float vv[4][4];
        #pragma unroll
        for (int t = 0; t < 4; t++) {
            int col = t * 16 + l16;
            float bpv = bp[col], bdv = bd[col];
            #pragma unroll
            for (int r = 0; r < 4; r++) {
                float v = ty[r] ? (accd[t][r] + bdv) : (accp[t][r] + bpv);
                vv[t][r] = v;
                h0f[(size_t)(row0 + quad * 4 + r) * 64 + col] = v;
                y0s[wv][(quad * 4 + r) * 72 + col] = (unsigned short)bf16r(v);
            }
        }
        s8 a0 = *(const s8*)&y0s[wv][l16 * 72 + quad * 8];
        s8 a1 = *(const s8*)&y0s[wv][l16 * 72 + 32 + quad * 8];
        f4 hw[4];
        #pragma unroll
        for (int t = 0; t < 4; t++) {
            hw[t] = f4{0.f,0.f,0.f,0.f};
            s8 b0 = *(const s8*)&WgT[(t * 16 + l16) * 72 + quad * 8];
            hw[t] = __builtin_amdgcn_mfma_f32_16x16x32_bf16(a0, b0, hw[t], 0, 0, 0);
            s8 b1_ = *(const s8*)&WgT[(t * 16 + l16) * 72 + 32 + quad * 8];
            hw[t] = __builtin_amdgcn_mfma_f32_16x16x32_bf16(a1, b1_, hw[t], 0, 0, 0);
        }
        #pragma unroll
        for (int t = 0; t < 4; t++) {
            int col = t * 16 + l16;
            float alv = al[col], arv = ar[col];
            #pragma unroll
            for (int r = 0; r < 4; r++) {
                int row = row0 + quad * 4 + r;
                float h = hw[t][r];
                P[(size_t)row * 64 + col] = bf16r(h) | (bf16r(vv[t][r]) << 16);
                float pl = h * alv, pr = h * arv;
                #pragma unroll
                for (int m = 1; m < 16; m <<= 1) {
                    pl += __shfl_xor(pl, m, 64);
                    pr += __shfl_xor(pr, m, 64);
                }
                if (l16 == 0) {
                    el[(size_t)row * 4 + t] = pl;
                    er[(size_t)row * 4 + t] = pr;
                }
            }
        }
    }
}

// ================= edge walk: 1 node/wave, exp once/edge, packed bf16 gather ======
template <int RELU>
__global__ void k_edges(const int* __restrict__ rows, const int* __restrict__ csr,
                        const unsigned* __restrict__ Pin,
                        const float* __restrict__ el, const float* __restrict__ er,
                        const float* __restrict__ gat_in, const float* __restrict__ gin_in,
                        const float* __restrict__ eps_p,
                        float* __restrict__ vgf, unsigned short* __restrict__ vgb,
                        unsigned short* __restrict__ xb) {
    __shared__ float ews[4][256];
    int wv = threadIdx.x >> 6, lane = threadIdx.x & 63;
    int n = blockIdx.x * 4 + wv;
    int st = rows[n], dg = rows[n + 1] - st;
    int hd = lane >> 4;
    float4 erv = *reinterpret_cast<const float4*>(er + (size_t)n * 4);
    float accg = 0.f, acci = 0.f, ssum = 0.f;
    for (int base = 0; base < dg; base += 64) {
        int rem = dg - base; if (rem > 64) rem = 64;
        int myi = 0;
        if (lane < rem) {
            myi = csr[st + base + lane];
            float4 lv = *reinterpret_cast<const float4*>(el + (size_t)myi * 4);
            float4 ev;
            ev.x = __expf(leaky(lv.x + erv.x));
            ev.y = __expf(leaky(lv.y + erv.y));
            ev.z = __expf(leaky(lv.z + erv.z));
            ev.w = __expf(leaky(lv.w + erv.w));
            *reinterpret_cast<float4*>(&ews[wv][lane * 4]) = ev;
        }
        int j = 0;
        for (; j + 4 <= rem; j += 4) {
            int s0 = __shfl(myi, j, 64),     s1 = __shfl(myi, j + 1, 64);
            int s2 = __shfl(myi, j + 2, 64), s3 = __shfl(myi, j + 3, 64);
            unsigned p0 = Pin[(size_t)s0 * 64 + lane];
            unsigned p1 = Pin[(size_t)s1 * 64 + lane];
            unsigned p2 = Pin[(size_t)s2 * 64 + lane];
            unsigned p3 = Pin[(size_t)s3 * 64 + lane];
            float a0 = ews[wv][(j + 0) * 4 + hd];
            float a1 = ews[wv][(j + 1) * 4 + hd];
            float a2 = ews[wv][(j + 2) * 4 + hd];
            float a3 = ews[wv][(j + 3) * 4 + hd];
            accg += a0 * lo16(p0) + a1 * lo16(p1) + a2 * lo16(p2) + a3 * lo16(p3);
            acci += hi16(p0) + hi16(p1) + hi16(p2) + hi16(p3);
            ssum += a0 + a1 + a2 + a3;
        }
        for (; j < rem; j++) {
            int s0 = __shfl(myi, j, 64);
            unsigned p0 = Pin[(size_t)s0 * 64 + lane];
            float a0 = ews[wv][j * 4 + hd];
            accg += a0 * lo16(p0); acci += hi16(p0); ssum += a0;
        }
    }
    float vg = accg / (ssum + 1e-9f) + gat_in[(size_t)n * 64 + lane];
    if (RELU) vg = fmaxf(vg, 0.f);
    float invd = 1.0f / fmaxf((float)dg, 1.0f);
    float x = (1.0f + eps_p[0]) * gin_in[(size_t)n * 64 + lane] + acci * invd;
    size_t off = (size_t)n * 64 + lane;
    vgf[off] = vg;
    vgb[off] = (unsigned short)bf16r(vg);
    xb[off] = (unsigned short)bf16r(x);
}

// ====== k_mlp: GIN MLP (y1 in LDS) + (L==0: GAT-l1 pre | L==1: fused MoE routing) ======
template <int L>
__global__ __launch_bounds__(256) void k_mlp(const unsigned short* __restrict__ Gx,
        const unsigned short* __restrict__ Eb,
        const float* __restrict__ W1, const float* __restrict__ b1,
        const float* __restrict__ W2, const float* __restrict__ b2,
        const float* __restrict__ gatW, const float* __restrict__ al,
        const float* __restrict__ ar,
        unsigned short* __restrict__ Fb, float* __restrict__ Cf,
        unsigned* __restrict__ P, float* __restrict__ el, float* __restrict__ er,
        const float* __restrict__ Zg, const float* __restrict__ ggW,
        const float* __restrict__ ggb, const float* __restrict__ igW,
        const float* __restrict__ igb,
        float* __restrict__ wgtg, float* __restrict__ wgti,
        float* __restrict__ stats) {
    __shared__ unsigned short W1T[64 * 72];
    __shared__ unsigned short W2T[64 * 72];
    __shared__ unsigned short WgT[(L == 0) ? 64 * 72 : 64];
    __shared__ unsigned short y1s[4][16 * 72];
    __shared__ float sstat[16];
    if (L == 1 && threadIdx.x < 16) sstat[threadIdx.x] = 0.f;
    for (int idx = threadIdx.x; idx < 64 * 64; idx += 256) {
        int k = idx >> 6, n = idx & 63;
        W1T[n * 72 + k] = (unsigned short)bf16r(W1[idx]);
        W2T[n * 72 + k] = (unsigned short)bf16r(W2[idx]);
        if (L == 0) WgT[n * 72 + k] = (unsigned short)bf16r(gatW[idx]);
    }
    __syncthreads();
    int wv = threadIdx.x >> 6, lane = threadIdx.x & 63;
    int quad = lane >> 4, l16 = lane & 15;
    int gw = blockIdx.x * 4 + wv;
    int mtEnd = gw * 2 + 2; if (mtEnd > 3125) mtEnd = 3125;
    float sp[2][4] = {{0,0,0,0},{0,0,0,0}};
    float sh[2][4] = {{0,0,0,0},{0,0,0,0}};
    for (int mt = gw * 2; mt < mtEnd; mt++) {
        int row0 = mt * 16;
        const unsigned short* arow = Gx + (size_t)(row0 + l16) * 64;
        s8 a0 = *(const s8*)(arow + quad * 8);
        s8 a1 = *(const s8*)(arow + 32 + quad * 8);
        f4 acc1[4];
        #pragma unroll
        for (int t = 0; t < 4; t++) {
            acc1[t] = f4{0.f,0.f,0.f,0.f};
            s8 b0 = *(const s8*)&W1T[(t * 16 + l16) * 72 + quad * 8];
            acc1[t] = __builtin_amdgcn_mfma_f32_16x16x32_bf16(a0, b0, acc1[t], 0, 0, 0);
            s8 b1_ = *(const s8*)&W1T[(t * 16 + l16) * 72 + 32 + quad * 8];
            acc1[t] = __builtin_amdgcn_mfma_f32_16x16x32_bf16(a1, b1_, acc1[t], 0, 0, 0);
        }
        #pragma unroll
        for (int t = 0; t < 4; t++) {
            float b1v = b1[t * 16 + l16];
            #pragma unroll
            for (int r = 0; r < 4; r++) {
                float v = fmaxf(acc1[t][r] + b1v, 0.f);
                y1s[wv][(quad * 4 + r) * 72 + t * 16 + l16] = (unsigned short)bf16r(v);
            }
        }
        s8 c0 = *(const s8*)&y1s[wv][l16 * 72 + quad * 8];
        s8 c1 = *(const s8*)&y1s[wv][l16 * 72 + 32 + quad * 8];
        f4 acc2[4];
        #pragma unroll
        for (int t = 0; t < 4; t++) {
            acc2[t] = f4{0.f,0.f,0.f,0.f};
            s8 b0 = *(const s8*)&W2T[(t * 16 + l16) * 72 + quad * 8];
            acc2[t] = __builtin_amdgcn_mfma_f32_16x16x32_bf16(c0, b0, acc2[t], 0, 0, 0);
            s8 b1_ = *(const s8*)&W2T[(t * 16 + l16) * 72 + 32 + quad * 8];
            acc2[t] = __builtin_amdgcn_mfma_f32_16x16x32_bf16(c1, b1_, acc2[t], 0, 0, 0);
        }
        unsigned short vb[4][4];
        float vout[4][4];
        #pragma unroll
        for (int t = 0; t < 4; t++) {
            int col = t * 16 + l16;
            float b2v = b2[col];
            #pragma unroll
            for (int r = 0; r < 4; r++) {
                float v = acc2[t][r] + b2v;
                if (L == 0) v = fmaxf(v, 0.f);
                size_t off = (size_t)(row0 + quad * 4 + r) * 64 + col;
                unsigned short vb16 = (unsigned short)bf16r(v);
                vb[t][r] = vb16;
                vout[t][r] = v;
                Fb[off] = vb16;
                if (L == 0) Cf[off] = v;
            }
        }
        if (L == 0) {
            const unsigned short* erow = Eb + (size_t)(row0 + l16) * 64;
            s8 e0 = *(const s8*)(erow + quad * 8);
            s8 e1 = *(const s8*)(erow + 32 + quad * 8);
            f4 hw[4];
            #pragma unroll
            for (int t = 0; t < 4; t++) {
                hw[t] = f4{0.f,0.f,0.f,0.f};
                s8 b0 = *(const s8*)&WgT[(t * 16 + l16) * 72 + quad * 8];
                hw[t] = __builtin_amdgcn_mfma_f32_16x16x32_bf16(e0, b0, hw[t], 0, 0, 0);
                s8 b1_ = *(const s8*)&WgT[(t * 16 + l16) * 72 + 32 + quad * 8];
                hw[t] = __builtin_amdgcn_mfma_f32_16x16x32_bf16(e1, b1_, hw[t], 0, 0, 0);
            }
            #pragma unroll
            for (int t = 0; t < 4; t++) {
                int col = t * 16 + l16;
                float alv = al[col], arv = ar[col];
                #pragma unroll
                for (int r = 0; r < 4; r++) {
                    int row = row0 + quad * 4 + r;
                    float h = hw[t][r];
                    P[(size_t)row * 64 + col] = bf16r(h) | ((unsigned)vb[t][r] << 16);
                    float pl = h * alv, pr = h * arv;
                    #pragma unroll
                    for (int m = 1; m < 16; m <<= 1) {
                        pl += __shfl_xor(pl, m, 64);
                        pr += __shfl_xor(pr, m, 64);
                    }
                    if (l16 == 0) {
                        el[(size_t)row * 4 + t] = pl;
                        er[(size_t)row * 4 + t] = pr;
                    }
                }
            }
        } else {
            // fused MoE routing: zg from global (B), zi from registers
            #pragma unroll
            for (int r = 0; r < 4; r++) {
                int row = row0 + quad * 4 + r;
                float pg[4] = {0,0,0,0}, pi[4] = {0,0,0,0};
                #pragma unroll
                for (int t = 0; t < 4; t++) {
                    int col = t * 16 + l16;
                    float zgv = Zg[(size_t)row * 64 + col];
                    float ziv = vout[t][r];
                    #pragma unroll
                    for (int e = 0; e < 4; e++) {
                        pg[e] += zgv * ggW[col * 4 + e];
                        pi[e] += ziv * igW[col * 4 + e];
                    }
                }
                #pragma unroll
                for (int m = 1; m < 16; m <<= 1) {
                    #pragma unroll
                    for (int e = 0; e < 4; e++) {
                        pg[e] += __shfl_xor(pg[e], m, 64);
                        pi[e] += __shfl_xor(pi[e], m, 64);
                    }
                }
                if (l16 == 0) {
                    #pragma unroll
                    for (int q = 0; q < 2; q++) {
                        float lg0 = (q ? pi[0] + igb[0] : pg[0] + ggb[0]);
                        float lg1 = (q ? pi[1] + igb[1] : pg[1] + ggb[1]);
                        float lg2 = (q ? pi[2] + igb[2] : pg[2] + ggb[2]);
                        float lg3 = (q ? pi[3] + igb[3] : pg[3] + ggb[3]);
                        float mx = fmaxf(fmaxf(lg0, lg1), fmaxf(lg2, lg3));
                        float ex0 = __expf(lg0 - mx), ex1 = __expf(lg1 - mx);
                        float ex2 = __expf(lg2 - mx), ex3 = __expf(lg3 - mx);
                        float inv = 1.0f / (ex0 + ex1 + ex2 + ex3);
                        float pr4[4] = {ex0 * inv, ex1 * inv, ex2 * inv, ex3 * inv};
                        int i1 = 0; float v1 = pr4[0];
                        #pragma unroll
                        for (int t = 1; t < 4; t++) if (pr4[t] > v1) { v1 = pr4[t]; i1 = t; }
                        int i2 = -1; float v2 = -1.f;
                        #pragma unroll
                        for (int t = 0; t < 4; t++) if (t != i1 && pr4[t] > v2) { v2 = pr4[t]; i2 = t; }
                        float wsum = v1 + v2;
                        float wq[4] = {0.f, 0.f, 0.f, 0.f};
                        wq[i1] = v1 / wsum; wq[i2] = v2 / wsum;
                        float* WD = q ? wgti : wgtg;
                        *reinterpret_cast<float4*>(WD + (size_t)row * 4) =
                            float4{wq[0], wq[1], wq[2], wq[3]};
                        #pragma unroll
                        for (int t = 0; t < 4; t++) sp[q][t] += pr4[t];
                        sh[q][i1] += 1.f; sh[q][i2] += 1.f;
                    }
                }
            }
        }
    }
    if (L == 1) {
        __syncthreads();
        if (l16 == 0) {
            #pragma unroll
            for (int q = 0; q < 2; q++)
                #pragma unroll
                for (int e = 0; e < 4; e++) {
                    atomicAdd(&sstat[q * 8 + e], sp[q][e]);
                    atomicAdd(&sstat[q * 8 + 4 + e], sh[q][e]);
                }
        }
        __syncthreads();
        if (threadIdx.x < 16) atomicAdd(&stats[threadIdx.x], sstat[threadIdx.x]);
    }
}

// ======= dense-all experts (MFMA), both problems in one grid =======
__global__ __launch_bounds__(256) void k_expert(const unsigned short* __restrict__ Eb,
        const unsigned short* __restrict__ Fb,
        const float* __restrict__ g_eW1, const float* __restrict__ g_eb1,
        const float* __restrict__ g_eW2, const float* __restrict__ g_eb2,
        const float* __restrict__ i_eW1, const float* __restrict__ i_eb1,
        const float* __restrict__ i_eW2, const float* __restrict__ i_eb2,
        const float* __restrict__ wgtg, const float* __restrict__ wgti,
        float* __restrict__ moegf, float* __restrict__ moeif,
        unsigned short* __restrict__ ub) {
    __shared__ unsigned short w1t[4 * 32 * 72];
    __shared__ unsigned short w2t[4 * 64 * 40];
    __shared__ unsigned short y1s[4][16 * 40];
    int p = (blockIdx.x >= NBE) ? 1 : 0;
    int bb = blockIdx.x - p * NBE;
    const unsigned short* Ab = p ? Fb : Eb;
    const float* eW1 = p ? i_eW1 : g_eW1;
    const float* eb1 = p ? i_eb1 : g_eb1;
    const float* eW2 = p ? i_eW2 : g_eW2;
    const float* eb2 = p ? i_eb2 : g_eb2;
    const float* wgt = p ? wgti : wgtg;
    float* moef = p ? moeif : moegf;
    int qoff = p ? 64 : 0;
    for (int g = threadIdx.x; g < 8192; g += 256) {
        int e = g >> 11, rem = g & 2047;
        int k = rem >> 5, n = rem & 31;
        w1t[e * 2304 + n * 72 + k] = (unsigned short)bf16r(eW1[g]);
    }
    for (int g = threadIdx.x; g < 8192; g += 256) {
        int e = g >> 11, rem = g & 2047;
        int k = rem >> 6, n = rem & 63;
        w2t[e * 2560 + n * 40 + k] = (unsigned short)bf16r(eW2[g]);
    }
    __syncthreads();
    int wv = threadIdx.x >> 6, lane = threadIdx.x & 63;
    int quad = lane >> 4, l16 = lane & 15;
    int gw = bb * 4 + wv;
    int mtEnd = gw * 4 + 4; if (mtEnd > 3125) mtEnd = 3125;
    for (int mt = gw * 4; mt < mtEnd; mt++) {
        int row0 = mt * 16;
        const unsigned short* arow = Ab + (size_t)(row0 + l16) * 64;
        s8 a0 = *(const s8*)(arow + quad * 8);
        s8 a1 = *(const s8*)(arow + 32 + quad * 8);
        f4 outacc[4];
        #pragma unroll
        for (int t = 0; t < 4; t++) outacc[t] = f4{0.f,0.f,0.f,0.f};
        for (int e = 0; e < 4; e++) {
            f4 acc1[2];
            #pragma unroll
            for (int t = 0; t < 2; t++) {
                acc1[t] = f4{0.f,0.f,0.f,0.f};
                s8 b0 = *(const s8*)&w1t[e * 2304 + (t * 16 + l16) * 72 + quad * 8];
                acc1[t] = __builtin_amdgcn_mfma_f32_16x16x32_bf16(a0, b0, acc1[t], 0, 0, 0);
                s8 b1_ = *(const s8*)&w1t[e * 2304 + (t * 16 + l16) * 72 + 32 + quad * 8];
                acc1[t] = __builtin_amdgcn_mfma_f32_16x16x32_bf16(a1, b1_, acc1[t], 0, 0, 0);
            }
            #pragma unroll
            for (int t = 0; t < 2; t++) {
                float b1v = eb1[e * 32 + t * 16 + l16];
                #pragma unroll
                for (int r = 0; r < 4; r++) {
                    float v = fmaxf(acc1[t][r] + b1v, 0.f);
                    y1s[wv][(quad * 4 + r) * 40 + t * 16 + l16] = (unsigned short)bf16r(v);
                }
            }
            s8 a2 = *(const s8*)&y1s[wv][l16 * 40 + quad * 8];
            f4 acc2[4];
            #pragma unroll
            for (int t = 0; t < 4; t++) {
                acc2[t] = f4{0.f,0.f,0.f,0.f};
                s8 b2_ = *(const s8*)&w2t[e * 2560 + (t * 16 + l16) * 40 + quad * 8];
                acc2[t] = __builtin_amdgcn_mfma_f32_16x16x32_bf16(a2, b2_, acc2[t], 0, 0, 0);
            }
            #pragma unroll
            for (int t = 0; t < 4; t++) {
                float b2v = eb2[e * 64 + t * 16 + l16];
                #pragma unroll
                for (int r = 0; r < 4; r++) {
                    float we = wgt[(size_t)(row0 + quad * 4 + r) * 4 + e];
                    outacc[t][r] += we * (acc2[t][r] + b2v);
                }
            }
        }
        #pragma unroll
        for (int t = 0; t < 4; t++) {
            int col = t * 16 + l16;
            #pragma unroll
            for (int r = 0; r < 4; r++) {
                int row = row0 + quad * 4 + r;
                float v = outacc[t][r];
                moef[(size_t)row * 64 + col] = v;
                ub[(size_t)row * 128 + qoff + col] = (unsigned short)bf16r(v);
            }
        }
    }
}

// ================= fusion gate (MFMA) + aux finalize (block 0) =================
__global__ __launch_bounds__(256) void k_fusion(const unsigned short* __restrict__ ubuf,
        const float* __restrict__ W1, const float* __restrict__ b1,
        const float* __restrict__ W2, const float* __restrict__ b2,
        const float* __restrict__ moegf, const float* __restrict__ moeif,
        float* __restrict__ out, const float* __restrict__ stats) {
    __shared__ unsigned short W1T[64 * 136];
    __shared__ unsigned short W2T[64 * 72];
    __shared__ unsigned short y1s[4][16 * 72];
    for (int idx = threadIdx.x; idx < 128 * 64; idx += 256) {
        int k = idx >> 6, n = idx & 63;
        W1T[n * 136 + k] = (unsigned short)bf16r(W1[idx]);
    }
    for (int idx = threadIdx.x; idx < 64 * 64; idx += 256) {
        int k = idx >> 6, n = idx & 63;
        W2T[n * 72 + k] = (unsigned short)bf16r(W2[idx]);
    }
    __syncthreads();
    int wv = threadIdx.x >> 6, lane = threadIdx.x & 63;
    int quad = lane >> 4, l16 = lane & 15;
    int gw = blockIdx.x * 4 + wv;
    int mtEnd = gw * 2 + 2; if (mtEnd > 3125) mtEnd = 3125;
    for (int mt = gw * 2; mt < mtEnd; mt++) {
        int row0 = mt * 16;
        const unsigned short* arow = ubuf + (size_t)(row0 + l16) * 128;
        f4 acc1[4];
        #pragma unroll
        for (int t = 0; t < 4; t++) acc1[t] = f4{0.f,0.f,0.f,0.f};
        #pragma unroll
        for (int ks = 0; ks < 4; ks++) {
            s8 a = *(const s8*)(arow + ks * 32 + quad * 8);
            #pragma unroll
            for (int t = 0; t < 4; t++) {
                s8 b = *(const s8*)&W1T[(t * 16 + l16) * 136 + ks * 32 + quad * 8];
                acc1[t] = __builtin_amdgcn_mfma_f32_16x16x32_bf16(a, b, acc1[t], 0, 0, 0);
            }
        }
        #pragma unroll
        for (int t = 0; t < 4; t++) {
            float b1v = b1[t * 16 + l16];
            #pragma unroll
            for (int r = 0; r < 4; r++) {
                float v = fmaxf(acc1[t][r] + b1v, 0.f);
                y1s[wv][(quad * 4 + r) * 72 + t * 16 + l16] = (unsigned short)bf16r(v);
            }
        }
        f4 acc2[4];
        #pragma unroll
        for (int t = 0; t < 4; t++) acc2[t] = f4{0.f,0.f,0.f,0.f};
        #pragma unroll
        for (int ks = 0; ks < 2; ks++) {
            s8 a = *(const s8*)&y1s[wv][l16 * 72 + ks * 32 + quad * 8];
            #pragma unroll
            for (int t = 0; t < 4; t++) {
                s8 b = *(const s8*)&W2T[(t * 16 + l16) * 72 + ks * 32 + quad * 8];
                acc2[t] = __builtin_amdgcn_mfma_f32_16x16x32_bf16(a, b, acc2[t], 0, 0, 0);
            }
        }
        #pragma unroll
        for (int t = 0; t < 4; t++) {
            int col = t * 16 + l16;
            float b2v = b2[col];
            #pragma unroll
            for (int r = 0; r < 4; r++) {
                int row = row0 + quad * 4 + r;
                float g = 1.0f / (1.0f + __expf(-(acc2[t][r] + b2v)));
                float zgv = moegf[(size_t)row * 64 + col];
                float ziv = moeif[(size_t)row * 64 + col];
                out[(size_t)row * 64 + col] = g * zgv * ziv + (1.0f - g) * g;
            }
        }
    }
    if (blockIdx.x == 0 && threadIdx.x < 64) {
        int t = threadIdx.x;
        float s = (t < 16) ? stats[t] : 0.f;
        float aux = 0.f;
        for (int q = 0; q < 2; q++) {
            float a = 0.f;
            for (int e = 0; e < 4; e++) {
                float pr = __shfl(s, q * 8 + e, 64);
                float f  = __shfl(s, q * 8 + 4 + e, 64);
                a += (f / (float)NN) * (pr / (float)NN);
            }
            aux += 4.0f * a;
        }
        if (t == 0) out[(size_t)NN * 64] = aux;
    }
}

extern "C" void kernel_launch(void* const* d_in, const int* in_sizes, int n_in,
                              void* d_out, int out_size, void* d_ws, size_t ws_size,
                              hipStream_t stream) {
    (void)in_sizes; (void)n_in; (void)out_size; (void)ws_size;
    const float* features  = (const float*)d_in[0];
    const int*   node_types= (const int*)d_in[1];
    const int*   src       = (const int*)d_in[2];
    const int*   dst       = (const int*)d_in[3];
    const float* W_person  = (const float*)d_in[4];
    const float* b_person  = (const float*)d_in[5];
    const float* W_disease = (const float*)d_in[6];
    const float* b_disease = (const float*)d_in[7];
    const float* gat_W     = (const float*)d_in[8];
    const float* gat_al    = (const float*)d_in[9];
    const float* gat_ar    = (const float*)d_in[10];
    const float* gin_eps   = (const float*)d_in[11];
    const float* gin_W1    = (const float*)d_in[12];
    const float* gin_b1    = (const float*)d_in[13];
    const float* gin_W2    = (const float*)d_in[14];
    const float* gin_b2    = (const float*)d_in[15];
    const float* gat_gW    = (const float*)d_in[16];
    const float* gat_gb    = (const float*)d_in[17];
    const float* gat_eW1   = (const float*)d_in[18];
    const float* gat_eb1   = (const float*)d_in[19];
    const float* gat_eW2   = (const float*)d_in[20];
    const float* gat_eb2   = (const float*)d_in[21];
    const float* gin_gW    = (const float*)d_in[22];
    const float* gin_gb    = (const float*)d_in[23];
    const float* gin_eW1   = (const float*)d_in[24];
    const float* gin_eb1   = (const float*)d_in[25];
    const float* gin_eW2   = (const float*)d_in[26];
    const float* gin_eb2   = (const float*)d_in[27];
    const float* fg_W1     = (const float*)d_in[28];
    const float* fg_b1     = (const float*)d_in[29];
    const float* fg_W2     = (const float*)d_in[30];
    const float* fg_b2     = (const float*)d_in[31];
    float* out = (float*)d_out;

    float* ws = (float*)d_ws;
    size_t o = 0;
    float* A = ws + o; o += (size_t)NN * 64;        // h0f; later ub (bf16 NN x 128)
    float* B = ws + o; o += (size_t)NN * 64;        // vg f32 chain; later moegf
    float* C = ws + o; o += (size_t)NN * 64;        // gin l0 f32; later moeif
    unsigned short* E  = (unsigned short*)(ws + o); o += (size_t)NN * 32;  // vgb
    unsigned short* F  = (unsigned short*)(ws + o); o += (size_t)NN * 32;  // ginb
    unsigned short* G  = (unsigned short*)(ws + o); o += (size_t)NN * 32;  // xb
    unsigned* P = (unsigned*)(ws + o); o += (size_t)NN * 64;  // packed hW|gin
    float* el = ws + o; o += (size_t)NN * 4;
    float* er = ws + o; o += (size_t)NN * 4;
    float* wgtg = ws + o; o += (size_t)NN * 4;
    float* wgti = ws + o; o += (size_t)NN * 4;
    // zeroed region: degcnt | stats (single memset)
    int* degcnt    = (int*)(ws + o); o += NN;
    float* stats   = ws + o; o += 16;
    int* row_start = (int*)(ws + o); o += NN + 4;
    int* bsums     = (int*)(ws + o); o += 256;
    int* bpre      = (int*)(ws + o); o += 256;
    int* csr_src   = (int*)(ws + o); o += EE;
    int* seg_off   = (int*)(ws + o); o += NSEG * NBKT + 64;
    int* seg_cnt   = (int*)(ws + o); o += NSEG * NBKT + 64;
    unsigned* gseg = (unsigned*)(ws + o); o += (size_t)NSEG * EPB;

    unsigned short* ub = (unsigned short*)A;  // reuse after edges(l0)

    const int NB_node = NN / 4;     // 12500

    hipMemsetAsync(degcnt, 0, sizeof(int) * NN + sizeof(float) * 16, stream);

    // CSR build: block-local counting sort, scans
    k_binA<<<NSEG, 256, 0, stream>>>(src, dst, degcnt, seg_off, seg_cnt, gseg);
    k_scan_a<<<NBLK_SCAN, 256, 0, stream>>>(degcnt, bsums);
    k_scan_b<<<1, 256, 0, stream>>>(bsums, bpre);
    k_scan_c<<<NBLK_SCAN, 256, 0, stream>>>(degcnt, bpre, row_start);

    // fused: CSR fill (blocks 0..97, parallel gather) + projection/GAT-l0 pre
    k_binB_pre<<<NBKT + NBG, 256, 0, stream>>>(row_start, seg_off, seg_cnt, gseg, csr_src,
                                               features, node_types, W_person, b_person,
                                               W_disease, b_disease, gat_W, gat_al, gat_ar,
                                               A, P, el, er);

    // ---- layer 0 ----
    k_edges<1><<<NB_node, 256, 0, stream>>>(row_start, csr_src, P, el, er, A, A,
                                            gin_eps, B, E, G);
    k_mlp<0><<<NBG, 256, 0, stream>>>(G, E, gin_W1, gin_b1, gin_W2, gin_b2,
                                      gat_W + 4096, gat_al + 64, gat_ar + 64,
                                      F, C, P, el, er,
                                      nullptr, nullptr, nullptr, nullptr, nullptr,
                                      nullptr, nullptr, nullptr);

    // ---- layer 1 (+fused MoE routing) ----
    k_edges<0><<<NB_node, 256, 0, stream>>>(row_start, csr_src, P, el, er, B, C,
                                            gin_eps + 1, B, E, G);
    k_mlp<1><<<NBG, 256, 0, stream>>>(G, nullptr, gin_W1 + 4096, gin_b1 + 64,
                                      gin_W2 + 4096, gin_b2 + 64,
                                      nullptr, nullptr, nullptr,
                                      F, nullptr, nullptr, nullptr, nullptr,
                                      B, gat_gW, gat_gb, gin_gW, gin_gb,
                                      wgtg, wgti, stats);

    // ---- dense-all experts ----
    k_expert<<<NBE * 2, 256, 0, stream>>>(E, F,
                                          gat_eW1, gat_eb1, gat_eW2, gat_eb2,
                                          gin_eW1, gin_eb1, gin_eW2, gin_eb2,
                                          wgtg, wgti, B, C, ub);

    // ---- fusion + aux ----
    k_fusion<<<NBG, 256, 0, stream>>>(ub, fg_W1, fg_b1, fg_W2, fg_b2, B, C, out, stats);
}